// Round 2
// 194.195 us; speedup vs baseline: 1.0265x; 1.0265x over previous
//
#include <hip/hip_runtime.h>

typedef unsigned short u16;
typedef __attribute__((ext_vector_type(8))) _Float16 f16x8;
typedef __attribute__((ext_vector_type(4))) float f32x4;

#define MFMA_F16 __builtin_amdgcn_mfma_f32_16x16x32_f16

static __device__ __forceinline__ u16 f2h(float f) {
    return __builtin_bit_cast(u16, (_Float16)f);
}
static __device__ __forceinline__ ushort4 f4_to_h4(const float4 v) {
    ushort4 r;
    r.x = f2h(v.x); r.y = f2h(v.y); r.z = f2h(v.z); r.w = f2h(v.w);
    return r;
}

// ---------------------------------------------------------------------------
// Kernel 0: prep_w — convert Wq/Wk/Wv/Wo (4 x 16384 float4) fp32 -> fp16.
// ---------------------------------------------------------------------------
__global__ __launch_bounds__(256) void prep_w(
    const float* __restrict__ wq, const float* __restrict__ wk,
    const float* __restrict__ wv, const float* __restrict__ wo,
    u16* __restrict__ w4)
{
    const int tid = blockIdx.x * 256 + threadIdx.x;   // 16384 threads
    for (int i = tid; i < 65536; i += 16384) {
        const float* src = (i < 16384) ? wq : (i < 32768) ? wk
                         : (i < 49152) ? wv : wo;
        ((ushort4*)w4)[i] = f4_to_h4(((const float4*)src)[i & 16383]);
    }
}

// ---------------------------------------------------------------------------
// Kernel 1: Q/K/V projection, fp16 MFMA, x read fp32 (converted in staging).
// ALL epilogues route through an LDS transpose (k-loop LDS is dead) so every
// global store is a coalesced int4:
//   z<2 : Ds[n_local][d]  64 x 264  -> row-major Qh/Kh stores
//   z==2: Dt[d][n_local] 256 x  72  -> Vt[b][d][n] stores (fused transpose)
// ---------------------------------------------------------------------------
__global__ __launch_bounds__(256) void proj_qkv(
    const float* __restrict__ X, const u16* __restrict__ w4,
    const float* __restrict__ bq, const float* __restrict__ bk,
    const float* __restrict__ bv,
    u16* __restrict__ Qh, u16* __restrict__ Kh, u16* __restrict__ Vt)
{
    const int z = blockIdx.y;
    const u16* __restrict__ W     = w4 + z * 65536;
    const float* __restrict__ bias = (z == 0) ? bq : (z == 1) ? bk : bv;

    const int m0   = blockIdx.x * 64;          // global row (b*2048 + n0)
    const int t    = threadIdx.x;
    const int w    = t >> 6;
    const int lane = t & 63;
    const int quad = lane >> 4;
    const int l16  = lane & 15;

    __shared__ __align__(16) u16 smem[18432];  // 36864 B
    u16* Xs = smem;            // 64 x 40 during k-loop
    u16* Ws = smem + 2560;     // 256 x 40 during k-loop

    f32x4 acc[16];
#pragma unroll
    for (int i = 0; i < 16; ++i) acc[i] = f32x4{0.f, 0.f, 0.f, 0.f};

    for (int kc = 0; kc < 8; ++kc) {
        // X tile fp32 -> fp16: 64 rows x 8 float4-chunks = 512, 2/thread
#pragma unroll
        for (int i = 0; i < 2; ++i) {
            const int ch = i * 256 + t;
            const int row = ch >> 3, cg = ch & 7;
            const float4 v = *(const float4*)&X[(size_t)(m0 + row) * 256 + kc * 32 + cg * 4];
            *(ushort4*)&Xs[row * 40 + cg * 4] = f4_to_h4(v);
        }
        // W tile (fp16 pre-converted): 1024 int4-chunks, 4/thread
#pragma unroll
        for (int i = 0; i < 4; ++i) {
            const int ch = i * 256 + t;
            const int row = ch >> 2, cg = ch & 3;
            *(int4*)&Ws[row * 40 + cg * 8] =
                *(const int4*)&W[(size_t)row * 256 + kc * 32 + cg * 8];
        }
        __syncthreads();

        const f16x8 af = *(const f16x8*)&Xs[(w * 16 + l16) * 40 + quad * 8];
#pragma unroll
        for (int nt = 0; nt < 16; ++nt) {
            const f16x8 bf = *(const f16x8*)&Ws[(nt * 16 + l16) * 40 + quad * 8];
            acc[nt] = MFMA_F16(af, bf, acc[nt], 0, 0, 0);
        }
        __syncthreads();   // also makes smem safe to reuse in the epilogue
    }

    if (z < 2) {
        u16* __restrict__ Y = (z == 0) ? Qh : Kh;
        // C-layout -> Ds[n][d] (scalar u16 stores, block-local)
#pragma unroll
        for (int nt = 0; nt < 16; ++nt) {
            const int col = nt * 16 + l16;
            const float bb = bias[col];
#pragma unroll
            for (int r = 0; r < 4; ++r)
                smem[(w * 16 + quad * 4 + r) * 264 + col] = f2h(acc[nt][r] + bb);
        }
        __syncthreads();
        // coalesced row-major stores: 64 rows x 32 int4 = 2048 chunks, 8/thread
#pragma unroll
        for (int i = 0; i < 8; ++i) {
            const int ch = i * 256 + t;
            const int row = ch >> 5, cg = ch & 31;
            *(int4*)&Y[(size_t)(m0 + row) * 256 + cg * 8] =
                *(const int4*)&smem[row * 264 + cg * 8];
        }
    } else {
        // C-layout -> Dt[d][n] (ushort4 over r), then coalesced Vt rows
        const int b  = m0 >> 11;
        const int n0 = m0 & 2047;
#pragma unroll
        for (int nt = 0; nt < 16; ++nt) {
            const int col = nt * 16 + l16;
            const float bb = bias[col];
            ushort4 h4;
            h4.x = f2h(acc[nt][0] + bb);
            h4.y = f2h(acc[nt][1] + bb);
            h4.z = f2h(acc[nt][2] + bb);
            h4.w = f2h(acc[nt][3] + bb);
            *(ushort4*)&smem[col * 72 + w * 16 + quad * 4] = h4;
        }
        __syncthreads();
        // 256 d-rows x 8 int4 chunks (64 n each) = 2048 chunks, 8/thread
#pragma unroll
        for (int i = 0; i < 8; ++i) {
            const int ch = i * 256 + t;
            const int row = ch >> 3, cg = ch & 7;
            *(int4*)&Vt[(size_t)b * 524288 + (size_t)row * 2048 + n0 + cg * 8] =
                *(const int4*)&smem[row * 72 + cg * 8];
        }
    }
}

// ---------------------------------------------------------------------------
// Kernel 2: flash attention, transposed scores.
// S^T = K Q^T, O^T = V^T P^T; split-K x nz (launched with nz=4).
// R14 (= R13 retry, workspace-hardened):
//   nz 2->4 for 4 blocks/CU occupancy (grid was the occupancy cap, not
//   resources: LDS 37.4KB and 112 VGPR both allow 4 blocks/CU).
//   Partials z=0,1 -> Op workspace; z=2,3 -> packed into d_out scratch
//   (one f32 out row = 1024B = exactly two 512B f16 partial rows; outproj
//   reads those rows block-locally before overwriting them -> no race).
//   l-stats -> dead Wq/Wk/Wv half of W4 region (proj done, Woh untouched);
//   m-stats -> old lmp slot. Total d_ws usage == 199µs baseline exactly.
//   defer-max (T13, THR=8) skips the O-rescale unless tile max grows >8.
//   s_setprio(1) around MFMA clusters (T5).
// ---------------------------------------------------------------------------
__global__ __launch_bounds__(256) void attn(
    const u16* __restrict__ Qh, const u16* __restrict__ Kg,
    const u16* __restrict__ Vt, u16* __restrict__ Op,
    u16* __restrict__ OutS, float* __restrict__ lmpL, float* __restrict__ lmpM)
{
    const int nz = gridDim.z;
    const int z  = blockIdx.z;
    const int tbase = 64 / nz, trem = 64 % nz;
    const int my_tiles = tbase + (z < trem ? 1 : 0);
    const int tile0    = tbase * z + (z < trem ? z : trem);

    const int b  = blockIdx.y;
    const int q0 = blockIdx.x * 64;
    const int t    = threadIdx.x;
    const int w    = t >> 6;
    const int lane = t & 63;
    const int quad = lane >> 4;
    const int l16  = lane & 15;

    __shared__ __align__(16) u16 smem[18688];   // 37376 B
    u16* Ks = smem;                // 32 x 264
    u16* Vs = smem + 8448;         // 256 x 40
    u16* Os = smem;                // epilogue reuse: 64 x 264

    f16x8 qf[8];
    {
        const size_t qrow = (size_t)(b * 2048 + q0 + w * 16 + l16) * 256;
#pragma unroll
        for (int kc = 0; kc < 8; ++kc)
            qf[kc] = *(const f16x8*)&Qh[qrow + kc * 32 + quad * 8];
    }

    f32x4 O[16];
#pragma unroll
    for (int i = 0; i < 16; ++i) O[i] = f32x4{0.f, 0.f, 0.f, 0.f};
    float mrow = -1e30f, lrow = 0.f;

    for (int it = 0; it < my_tiles; ++it) {
        const int kt = (tile0 + it) * 32;
#pragma unroll
        for (int i = 0; i < 4; ++i) {
            const int ch = i * 256 + t;
            const int row = ch >> 5, cg = ch & 31;
            const int prow = ((row >> 2) & 3) * 8 + (row >> 4) * 4 + (row & 3);
            *(int4*)&Ks[row * 264 + cg * 8] =
                *(const int4*)&Kg[(size_t)(b * 2048 + kt + prow) * 256 + cg * 8];
        }
#pragma unroll
        for (int i = 0; i < 4; ++i) {
            const int ch = i * 256 + t;
            const int row = ch >> 2, cg = ch & 3;
            *(int4*)&Vs[row * 40 + cg * 8] =
                *(const int4*)&Vt[(size_t)b * 524288 + (size_t)row * 2048 + kt + cg * 8];
        }
        __syncthreads();

        f32x4 S[2];
        S[0] = f32x4{0.f, 0.f, 0.f, 0.f};
        S[1] = f32x4{0.f, 0.f, 0.f, 0.f};
        __builtin_amdgcn_s_setprio(1);
#pragma unroll
        for (int kc = 0; kc < 8; ++kc) {
#pragma unroll
            for (int kn = 0; kn < 2; ++kn) {
                const f16x8 kf = *(const f16x8*)&Ks[(kn * 16 + l16) * 264 + kc * 32 + quad * 8];
                S[kn] = MFMA_F16(kf, qf[kc], S[kn], 0, 0, 0);
            }
        }
        __builtin_amdgcn_s_setprio(0);

        float mt = fmaxf(fmaxf(fmaxf(S[0][0], S[0][1]), fmaxf(S[0][2], S[0][3])),
                         fmaxf(fmaxf(S[1][0], S[1][1]), fmaxf(S[1][2], S[1][3])));
        mt = fmaxf(mt, __shfl_xor(mt, 16));
        mt = fmaxf(mt, __shfl_xor(mt, 32));
        // T13 defer-max: only rescale when the tile max grows past mrow+8.
        // P is then bounded by e^8 (~2981), safely inside f16 range; O/l are
        // both consistently relative to mrow, so the final normalization and
        // the split-K combine are unchanged.
        if (__any(mt - mrow > 8.f)) {
            const float mnew = fmaxf(mrow, mt);
            const float a = __expf(mrow - mnew);
            lrow *= a;
#pragma unroll
            for (int dv = 0; dv < 16; ++dv)
#pragma unroll
                for (int r = 0; r < 4; ++r) O[dv][r] *= a;
            mrow = mnew;
        }
        float p[2][4];
        float s = 0.f;
#pragma unroll
        for (int kn = 0; kn < 2; ++kn)
#pragma unroll
            for (int r = 0; r < 4; ++r) {
                p[kn][r] = __expf(S[kn][r] - mrow);
                s += p[kn][r];
            }
        s += __shfl_xor(s, 16);
        s += __shfl_xor(s, 32);
        lrow += s;

        f16x8 pf;
#pragma unroll
        for (int kn = 0; kn < 2; ++kn)
#pragma unroll
            for (int r = 0; r < 4; ++r)
                pf[kn * 4 + r] = (_Float16)p[kn][r];

        __builtin_amdgcn_s_setprio(1);
#pragma unroll
        for (int dvt = 0; dvt < 16; ++dvt) {
            const f16x8 vf = *(const f16x8*)&Vs[(dvt * 16 + l16) * 40 + quad * 8];
            O[dvt] = MFMA_F16(vf, pf, O[dvt], 0, 0, 0);
        }
        __builtin_amdgcn_s_setprio(0);
        __syncthreads();
    }

    {
        const float rl = 1.0f / lrow;
#pragma unroll
        for (int dvt = 0; dvt < 16; ++dvt) {
            ushort4 h4;
            h4.x = f2h(O[dvt][0] * rl);
            h4.y = f2h(O[dvt][1] * rl);
            h4.z = f2h(O[dvt][2] * rl);
            h4.w = f2h(O[dvt][3] * rl);
            *(ushort4*)&Os[(w * 16 + l16) * 264 + dvt * 16 + quad * 4] = h4;
        }
        if (quad == 0) {
            const int grow = b * 2048 + q0 + w * 16 + l16;
            lmpL[z * 16384 + grow] = lrow;
            lmpM[z * 16384 + grow] = mrow;
        }
    }
    __syncthreads();

    {
        const int row = t >> 2;
        if (z < 2) {
            u16* __restrict__ Oz = Op + (size_t)z * 4194304;
#pragma unroll
            for (int i = 0; i < 8; ++i) {
                const int chunk = (t & 3) * 8 + i;
                *(int4*)&Oz[(size_t)(b * 2048 + q0 + row) * 256 + chunk * 8] =
                    *(const int4*)&Os[row * 264 + chunk * 8];
            }
        } else {
            // packed into d_out scratch: row m -> u16[m*512 + (z-2)*256 ...]
            u16* __restrict__ Oz = OutS + (size_t)(z - 2) * 256;
#pragma unroll
            for (int i = 0; i < 8; ++i) {
                const int chunk = (t & 3) * 8 + i;
                *(int4*)&Oz[(size_t)(b * 2048 + q0 + row) * 512 + chunk * 8] =
                    *(const int4*)&Os[row * 264 + chunk * 8];
            }
        }
    }
}

// ---------------------------------------------------------------------------
// Kernel 3: combine 4 partials + out projection + LayerNorm + LeakyReLU.
// Partials 0,1 from Op workspace; 2,3 packed in d_out scratch (read fully
// for rows m0..m0+63 in the k-loop before the epilogue overwrites exactly
// those rows with f32 output -> no intra- or inter-block hazard).
// ---------------------------------------------------------------------------
__global__ __launch_bounds__(256) void outproj_ln(
    const u16* __restrict__ Op, const u16* __restrict__ OutS,
    const float* __restrict__ lmpL, const float* __restrict__ lmpM,
    const u16* __restrict__ Woh, const float* __restrict__ bo,
    const float* __restrict__ gamma, const float* __restrict__ beta,
    float* __restrict__ out)
{
    const int m0   = blockIdx.x * 64;
    const int t    = threadIdx.x;
    const int w    = t >> 6;
    const int lane = t & 63;
    const int quad = lane >> 4;
    const int l16  = lane & 15;

    __shared__ __align__(16) u16 Ls[64 * 40];
    __shared__ __align__(16) u16 Ws[256 * 40];
    __shared__ _Float16 wls[4][64];

    if (t < 64) {
        const float l0 = lmpL[m0 + t],         l1 = lmpL[16384 + m0 + t];
        const float l2 = lmpL[32768 + m0 + t], l3 = lmpL[49152 + m0 + t];
        const float m0v = lmpM[m0 + t],          m1v = lmpM[16384 + m0 + t];
        const float m2v = lmpM[32768 + m0 + t],  m3v = lmpM[49152 + m0 + t];
        const float mm = fmaxf(fmaxf(m0v, m1v), fmaxf(m2v, m3v));
        const float u0 = l0 * __expf(m0v - mm);
        const float u1 = l1 * __expf(m1v - mm);
        const float u2 = l2 * __expf(m2v - mm);
        const float u3 = l3 * __expf(m3v - mm);
        const float inv = 1.0f / (u0 + u1 + u2 + u3);
        wls[0][t] = (_Float16)(u0 * inv);
        wls[1][t] = (_Float16)(u1 * inv);
        wls[2][t] = (_Float16)(u2 * inv);
        wls[3][t] = (_Float16)(u3 * inv);
    }
    __syncthreads();

    f32x4 acc[16];
#pragma unroll
    for (int i = 0; i < 16; ++i) acc[i] = f32x4{0.f, 0.f, 0.f, 0.f};

    for (int kc = 0; kc < 8; ++kc) {
        {
            const int row = t >> 2, cg = t & 3;
            const size_t off  = (size_t)(m0 + row) * 256 + kc * 32 + cg * 8;
            const size_t offS = (size_t)(m0 + row) * 512 + kc * 32 + cg * 8;
            const f16x8 o0 = __builtin_bit_cast(f16x8, *(const int4*)&Op[off]);
            const f16x8 o1 = __builtin_bit_cast(f16x8, *(const int4*)&Op[4194304 + off]);
            const f16x8 o2 = __builtin_bit_cast(f16x8, *(const int4*)&OutS[offS]);
            const f16x8 o3 = __builtin_bit_cast(f16x8, *(const int4*)&OutS[offS + 256]);
            const _Float16 w0 = wls[0][row], w1 = wls[1][row];
            const _Float16 w2 = wls[2][row], w3 = wls[3][row];
            f16x8 lw;
#pragma unroll
            for (int j = 0; j < 8; ++j)
                lw[j] = o0[j] * w0 + o1[j] * w1 + o2[j] * w2 + o3[j] * w3;
            *(int4*)&Ls[row * 40 + cg * 8] = __builtin_bit_cast(int4, lw);
        }
#pragma unroll
        for (int i = 0; i < 4; ++i) {
            const int ch = i * 256 + t;
            const int row = ch >> 2, cg = ch & 3;
            *(int4*)&Ws[row * 40 + cg * 8] =
                *(const int4*)&Woh[(size_t)row * 256 + kc * 32 + cg * 8];
        }
        __syncthreads();

        const f16x8 af = *(const f16x8*)&Ls[(w * 16 + l16) * 40 + quad * 8];
#pragma unroll
        for (int nt = 0; nt < 16; ++nt) {
            const f16x8 bf = *(const f16x8*)&Ws[(nt * 16 + l16) * 40 + quad * 8];
            acc[nt] = MFMA_F16(af, bf, acc[nt], 0, 0, 0);
        }
        __syncthreads();
    }

    float g[16], bt[16], bb[16];
#pragma unroll
    for (int nt = 0; nt < 16; ++nt) {
        const int col = nt * 16 + l16;
        bb[nt] = bo[col]; g[nt] = gamma[col]; bt[nt] = beta[col];
    }

#pragma unroll
    for (int r = 0; r < 4; ++r) {
        float h[16];
        float sh = 0.f, sh2 = 0.f;
#pragma unroll
        for (int nt = 0; nt < 16; ++nt) {
            h[nt] = acc[nt][r] + bb[nt];
            sh  += h[nt];
            sh2 += h[nt] * h[nt];
        }
        sh  += __shfl_xor(sh, 1);  sh  += __shfl_xor(sh, 2);
        sh  += __shfl_xor(sh, 4);  sh  += __shfl_xor(sh, 8);
        sh2 += __shfl_xor(sh2, 1); sh2 += __shfl_xor(sh2, 2);
        sh2 += __shfl_xor(sh2, 4); sh2 += __shfl_xor(sh2, 8);
        const float mu  = sh * (1.f / 256.f);
        const float var = fmaxf(sh2 * (1.f / 256.f) - mu * mu, 0.f);
        const float rs  = rsqrtf(var + 1e-5f);
        const size_t row = (size_t)(m0 + w * 16 + quad * 4 + r) * 256;
#pragma unroll
        for (int nt = 0; nt < 16; ++nt) {
            const float hn = (h[nt] - mu) * rs * g[nt] + bt[nt];
            out[row + nt * 16 + l16] = (hn >= 0.f) ? hn : 0.01f * hn;
        }
    }
}

// ---------------------------------------------------------------------------
extern "C" void kernel_launch(void* const* d_in, const int* in_sizes, int n_in,
                              void* d_out, int out_size, void* d_ws, size_t ws_size,
                              hipStream_t stream)
{
    const float* x  = (const float*)d_in[0];
    const float* Wq = (const float*)d_in[1];
    const float* bq = (const float*)d_in[2];
    const float* Wk = (const float*)d_in[3];
    const float* bk = (const float*)d_in[4];
    const float* Wv = (const float*)d_in[5];
    const float* bv = (const float*)d_in[6];
    const float* Wo = (const float*)d_in[7];
    const float* bo = (const float*)d_in[8];
    const float* gm = (const float*)d_in[9];
    const float* bt = (const float*)d_in[10];
    float* out = (float*)d_out;

    // ws layout (u16): [W4 262144][Qh 4.19M][Kh 4.19M][Vt 4.19M][Op 2x4.19M][lmpM]
    // -> identical total d_ws footprint to the 199µs baseline.
    // l-stats (l[4][16384] f32, 256KB) live in the dead Wq/Wk/Wv half of W4
    // (first 196608 u16 = 384KB, dead after proj_qkv; Woh at +196608 intact).
    // split-K partials z=2,3 live packed inside d_out (scratch until outproj).
    u16* W4 = (u16*)d_ws;
    u16* Qh = W4 + 262144;
    u16* Kh = Qh + 4194304;
    u16* Vt = Kh + 4194304;
    u16* Op = Vt + 4194304;
    float* lmpM = (float*)(Op + 2 * 4194304);  // m[4][16384] (old lmp slot)
    float* lmpL = (float*)W4;                  // l[4][16384] (dead W region)
    u16* Woh = W4 + 196608;
    u16* OutS = (u16*)d_out;

    prep_w     <<<64,             256, 0, stream>>>(Wq, Wk, Wv, Wo, W4);
    proj_qkv   <<<dim3(256, 3),   256, 0, stream>>>(x, W4, bq, bk, bv, Qh, Kh, Vt);
    attn       <<<dim3(32, 8, 4), 256, 0, stream>>>(Qh, Kh, Vt, Op, OutS, lmpL, lmpM);
    outproj_ln <<<256,            256, 0, stream>>>(Op, OutS, lmpL, lmpM, Woh, bo, gm, bt, out);
}